// Round 5
// baseline (512.950 us; speedup 1.0000x reference)
//
#include <hip/hip_runtime.h>

// Problem constants
#define NPOS 32768          // B*H*W = 32*32*32
#define DDIM 256
#define KCODE 1024
#define HW 1024             // H*W
#define BSTRIDE (256*1024)  // D*H*W per batch element
#define OUT0_SIZE 8388608   // B*D*H*W
#define OUT1_SIZE 32768

// ws layout (4-byte units):
//  [0 .. 262143]        ET    : transposed codebook [d][k]    (float)
//  [262144 .. 294911]   zn    : ||z_n||^2 numpy-pairwise f32  (float, 32768)
//  [294912 .. 295935]   en    : ||e_k||^2 numpy-pairwise f32  (float, 1024)
//  [295936 .. 361471]   packed: (f32bits(d)<<32)|k per pos    (u64, 32768)
#define WS_ET     0
#define WS_ZN     262144
#define WS_EN     294912
#define WS_PACKED 295936   // 8-byte aligned

// ---------------------------------------------------------------------------
// K1: fused prep. grid 196 blocks x 256 threads:
//   blocks [0,128)   : zn[n] numpy-pairwise + packed init (+ loss zero @ n=0)
//   blocks [128,132) : en[k] numpy-pairwise
//   blocks [132,196) : 64x64 LDS-tiled transpose cb -> ET
// __fadd_rn/__fmul_rn: IEEE f32 RTE, no contraction -> bitwise == numpy CPU.
__global__ void vq_prep(const float* __restrict__ z,
                        const float* __restrict__ cb,
                        float* __restrict__ ws_f,
                        unsigned long long* __restrict__ packed,
                        float* __restrict__ loss_slot) {
    __shared__ float tile[64][65];
    int bx = blockIdx.x;
    int t  = threadIdx.x;

    if (bx < 128) {                       // ---- zn role
        int n = bx * 256 + t;
        int b = n >> 10, hw = n & 1023;
        const float* zp = z + (size_t)b * BSTRIDE + hw;
        float half_s[2];
        #pragma unroll
        for (int h = 0; h < 2; ++h) {
            const float* p = zp + (size_t)(h * 128) * HW;
            float r[8];
            #pragma unroll
            for (int j = 0; j < 8; ++j) {
                float v = p[(size_t)j * HW];
                r[j] = __fmul_rn(v, v);
            }
            #pragma unroll
            for (int i = 8; i < 128; i += 8) {
                #pragma unroll
                for (int j = 0; j < 8; ++j) {
                    float v = p[(size_t)(i + j) * HW];
                    r[j] = __fadd_rn(r[j], __fmul_rn(v, v));
                }
            }
            half_s[h] = __fadd_rn(
                __fadd_rn(__fadd_rn(r[0], r[1]), __fadd_rn(r[2], r[3])),
                __fadd_rn(__fadd_rn(r[4], r[5]), __fadd_rn(r[6], r[7])));
        }
        ws_f[WS_ZN + n] = __fadd_rn(half_s[0], half_s[1]);
        packed[n] = 0xFFFFFFFFFFFFFFFFull;
        if (n == 0) *loss_slot = 0.0f;
    } else if (bx < 132) {                // ---- en role
        int k = (bx - 128) * 256 + t;
        const float* row = cb + (size_t)k * DDIM;
        float half_s[2];
        #pragma unroll
        for (int h = 0; h < 2; ++h) {
            const float* p = row + h * 128;
            float r[8];
            #pragma unroll
            for (int j = 0; j < 8; ++j) r[j] = __fmul_rn(p[j], p[j]);
            #pragma unroll
            for (int i = 8; i < 128; i += 8) {
                #pragma unroll
                for (int j = 0; j < 8; ++j)
                    r[j] = __fadd_rn(r[j], __fmul_rn(p[i + j], p[i + j]));
            }
            half_s[h] = __fadd_rn(
                __fadd_rn(__fadd_rn(r[0], r[1]), __fadd_rn(r[2], r[3])),
                __fadd_rn(__fadd_rn(r[4], r[5]), __fadd_rn(r[6], r[7])));
        }
        ws_f[WS_EN + k] = __fadd_rn(half_s[0], half_s[1]);
    } else {                              // ---- transpose role
        int bt = bx - 132;
        int k0 = (bt & 15) * 64;
        int d0 = (bt >> 4) * 64;
        float* et = ws_f + WS_ET;
        #pragma unroll
        for (int p = 0; p < 4; ++p) {
            int r  = p * 16 + (t >> 4);
            int c4 = (t & 15) * 4;
            float4 v = *reinterpret_cast<const float4*>(
                cb + (size_t)(k0 + r) * DDIM + d0 + c4);
            tile[r][c4] = v.x; tile[r][c4+1] = v.y;
            tile[r][c4+2] = v.z; tile[r][c4+3] = v.w;
        }
        __syncthreads();
        #pragma unroll
        for (int s = 0; s < 16; ++s) {
            int dd = s * 4 + (t >> 6);
            int kk = t & 63;
            et[(size_t)(d0 + dd) * KCODE + k0 + kk] = tile[kk][dd];
        }
    }
}

// ---------------------------------------------------------------------------
// K2: code-split distance-GEMM + argmin. Block: 64 positions x 256 codes
// (one quarter), full D. Per-(n,k): sequential fmaf chain d=0..255, then
// fl(fl(zn+en)-fl(2*dot)) — BIT-IDENTICAL to the verified round-3/4 kernels.
// A-operand read straight from global (d-major z, 2 distinct 16B addrs/wave
// -> L1-coalesced broadcast) — removes half the DS traffic that capped
// round 4 at VALUBusy=67%. B stays LDS-staged with the proven 9/8 skew
// (lane tx reads at 9*tx floats: 9 coprime 32 -> conflict-free).
// Cross-block merge: atomicMin on (f32bits(d)<<32)|k (d>0 -> monotone bits;
// ties -> smaller k == np.argmin first-index).
#define BM 64
#define BN 256
#define BK 16
#define BSKEW(k) ((k) + ((k) >> 3))

__launch_bounds__(256, 4)
__global__ void vq_argmin(const float* __restrict__ z,
                          const float* __restrict__ ws_f,
                          unsigned long long* __restrict__ packed) {
    __shared__ float Bs[BK][288];    // [dk][skewed code]

    const float* ET  = ws_f + WS_ET;
    const float* znW = ws_f + WS_ZN;
    const float* enW = ws_f + WS_EN;

    int t  = threadIdx.x;
    int tx = t & 31;                 // code group (8 codes each)
    int ty = t >> 5;                 // position group (8 positions each)
    int bc = blockIdx.x & 3;         // code-range quarter
    int bm = blockIdx.x >> 2;
    int kc = bc * BN;
    int n0 = bm * BM;
    int b  = n0 >> 10, hw0 = n0 & 1023;
    const float* zb = z + (size_t)b * BSTRIDE + hw0;
    const float* za = zb + ty * 8;   // this thread's 8 positions, d-major

    float znr[8];
    #pragma unroll
    for (int j = 0; j < 8; ++j) znr[j] = znW[n0 + ty * 8 + j];

    float acc[8][8];
    #pragma unroll
    for (int j = 0; j < 8; ++j)
        #pragma unroll
        for (int c = 0; c < 8; ++c) acc[j][c] = 0.0f;

    for (int d0 = 0; d0 < DDIM; d0 += BK) {
        __syncthreads();
        #pragma unroll
        for (int i = 0; i < 4; ++i) {   // stage B: 16x256 floats, skewed
            int q = t + i * 256;
            int dk = q >> 6, m = q & 63;          // codes 4m..4m+3
            float4 v = *reinterpret_cast<const float4*>(
                ET + (size_t)(d0 + dk) * KCODE + kc + 4 * m);
            int ph = BSKEW(4 * m);                // contiguous float4 slot
            *reinterpret_cast<float4*>(&Bs[dk][ph]) = v;
        }
        __syncthreads();

        #pragma unroll
        for (int dk = 0; dk < BK; ++dk) {
            float4 a0 = *reinterpret_cast<const float4*>(
                za + (size_t)(d0 + dk) * HW);
            float4 a1 = *reinterpret_cast<const float4*>(
                za + (size_t)(d0 + dk) * HW + 4);
            float4 b0 = *reinterpret_cast<const float4*>(&Bs[dk][9 * tx]);
            float4 b1 = *reinterpret_cast<const float4*>(&Bs[dk][9 * tx + 4]);
            float a[8]  = {a0.x, a0.y, a0.z, a0.w, a1.x, a1.y, a1.z, a1.w};
            float bb[8] = {b0.x, b0.y, b0.z, b0.w, b1.x, b1.y, b1.z, b1.w};
            #pragma unroll
            for (int j = 0; j < 8; ++j)
                #pragma unroll
                for (int c = 0; c < 8; ++c)
                    acc[j][c] = fmaf(a[j], bb[c], acc[j][c]);
        }
    }

    // epilogue: d = fl(fl(zn+en) - fl(2*dot)); strict < keeps first index
    float m1[8];
    int   i1[8];
    #pragma unroll
    for (int j = 0; j < 8; ++j) { m1[j] = 1e30f; i1[j] = 0; }
    #pragma unroll
    for (int c = 0; c < 8; ++c) {
        int k = kc + tx * 8 + c;
        float ek = enW[k];
        #pragma unroll
        for (int j = 0; j < 8; ++j) {
            float t1 = __fadd_rn(znr[j], ek);
            float d  = __fsub_rn(t1, __fmul_rn(2.0f, acc[j][c]));
            if (d < m1[j]) { m1[j] = d; i1[j] = k; }
        }
    }

    // cross-lane argmin over the 32 tx lanes (smaller index wins ties)
    #pragma unroll
    for (int j = 0; j < 8; ++j) {
        float a1 = m1[j];
        int   ii = i1[j];
        #pragma unroll
        for (int off = 1; off < 32; off <<= 1) {
            float o1 = __shfl_xor(a1, off, 32);
            int   oi = __shfl_xor(ii, off, 32);
            if (o1 < a1 || (o1 == a1 && oi < ii)) { a1 = o1; ii = oi; }
        }
        if (tx == 0) {
            unsigned long long key =
                ((unsigned long long)__float_as_uint(a1) << 32) |
                (unsigned long long)(unsigned)ii;
            atomicMin(&packed[n0 + ty * 8 + j], key);
        }
    }
}

// ---------------------------------------------------------------------------
// K3: final index extract + gather zq, transpose to (B,D,H,W), indices as
// float, loss = 2*mean((zq-zp)^2). Codebook row read as float4 (element
// order inside preserved: x,y,z,w processed in ascending d).
__global__ void vq_gather(const float* __restrict__ z,
                          const float* __restrict__ cb,
                          const unsigned long long* __restrict__ packed,
                          float* __restrict__ out,
                          float* __restrict__ loss) {
    int n = blockIdx.x * 256 + threadIdx.x;
    int b = n >> 10, hw = n & 1023;
    int k = (int)(unsigned)(packed[n] & 0xFFFFFFFFull);
    const float* e  = cb + (size_t)k * DDIM;
    const float* zp = z + (size_t)b * BSTRIDE + hw;
    float* op = out + (size_t)b * BSTRIDE + hw;
    float s = 0.0f;
    #pragma unroll 4
    for (int d4 = 0; d4 < DDIM / 4; ++d4) {
        float4 ev = *reinterpret_cast<const float4*>(e + 4 * d4);
        float evs[4] = {ev.x, ev.y, ev.z, ev.w};
        #pragma unroll
        for (int q = 0; q < 4; ++q) {
            int d = 4 * d4 + q;
            float zv = zp[(size_t)d * HW];
            op[(size_t)d * HW] = evs[q];
            float df = evs[q] - zv;
            s = fmaf(df, df, s);
        }
    }
    out[OUT0_SIZE + n] = (float)k;

    #pragma unroll
    for (int off = 32; off > 0; off >>= 1) s += __shfl_down(s, off);
    __shared__ float red[4];
    int lane = threadIdx.x & 63, w = threadIdx.x >> 6;
    if (lane == 0) red[w] = s;
    __syncthreads();
    if (threadIdx.x == 0) {
        float tot = (red[0] + red[1] + red[2] + red[3]) * (2.0f / 8388608.0f);
        atomicAdd(loss, tot);
    }
}

// ---------------------------------------------------------------------------
extern "C" void kernel_launch(void* const* d_in, const int* in_sizes, int n_in,
                              void* d_out, int out_size, void* d_ws, size_t ws_size,
                              hipStream_t stream) {
    const float* z  = (const float*)d_in[0];
    const float* cb = (const float*)d_in[1];
    float* out  = (float*)d_out;
    float* ws_f = (float*)d_ws;
    unsigned long long* packed =
        (unsigned long long*)(ws_f + WS_PACKED);
    float* loss = out + OUT0_SIZE + OUT1_SIZE;

    vq_prep<<<196, 256, 0, stream>>>(z, cb, ws_f, packed, loss);
    vq_argmin<<<(NPOS / BM) * (KCODE / BN), 256, 0, stream>>>(z, ws_f, packed);
    vq_gather<<<NPOS / 256, 256, 0, stream>>>(z, cb, packed, out, loss);
}

// Round 6
// 389.173 us; speedup vs baseline: 1.3181x; 1.3181x over previous
//
#include <hip/hip_runtime.h>

// Problem constants
#define NPOS 32768          // B*H*W = 32*32*32
#define DDIM 256
#define KCODE 1024
#define HW 1024             // H*W
#define BSTRIDE (256*1024)  // D*H*W per batch element
#define OUT0_SIZE 8388608   // B*D*H*W
#define OUT1_SIZE 32768

// ws layout (4-byte units):
//  [0 .. 262143]        ET    : transposed codebook [d][k]    (float)
//  [262144 .. 294911]   zn    : ||z_n||^2 numpy-pairwise f32  (float, 32768)
//  [294912 .. 295935]   en    : ||e_k||^2 numpy-pairwise f32  (float, 1024)
//  [295936 .. 361471]   packed: (f32bits(d)<<32)|k per pos    (u64, 32768)
#define WS_ET     0
#define WS_ZN     262144
#define WS_EN     294912
#define WS_PACKED 295936   // 8-byte aligned

// ---------------------------------------------------------------------------
// K1: fused prep. grid 196 blocks x 256 threads:
//   blocks [0,128)   : zn[n] numpy-pairwise + packed init (+ loss zero @ n=0)
//   blocks [128,132) : en[k] numpy-pairwise
//   blocks [132,196) : 64x64 LDS-tiled transpose cb -> ET
// __fadd_rn/__fmul_rn: IEEE f32 RTE, no contraction -> bitwise == numpy CPU.
__global__ void vq_prep(const float* __restrict__ z,
                        const float* __restrict__ cb,
                        float* __restrict__ ws_f,
                        unsigned long long* __restrict__ packed,
                        float* __restrict__ loss_slot) {
    __shared__ float tile[64][65];
    int bx = blockIdx.x;
    int t  = threadIdx.x;

    if (bx < 128) {                       // ---- zn role
        int n = bx * 256 + t;
        int b = n >> 10, hw = n & 1023;
        const float* zp = z + (size_t)b * BSTRIDE + hw;
        float half_s[2];
        #pragma unroll
        for (int h = 0; h < 2; ++h) {
            const float* p = zp + (size_t)(h * 128) * HW;
            float r[8];
            #pragma unroll
            for (int j = 0; j < 8; ++j) {
                float v = p[(size_t)j * HW];
                r[j] = __fmul_rn(v, v);
            }
            #pragma unroll
            for (int i = 8; i < 128; i += 8) {
                #pragma unroll
                for (int j = 0; j < 8; ++j) {
                    float v = p[(size_t)(i + j) * HW];
                    r[j] = __fadd_rn(r[j], __fmul_rn(v, v));
                }
            }
            half_s[h] = __fadd_rn(
                __fadd_rn(__fadd_rn(r[0], r[1]), __fadd_rn(r[2], r[3])),
                __fadd_rn(__fadd_rn(r[4], r[5]), __fadd_rn(r[6], r[7])));
        }
        ws_f[WS_ZN + n] = __fadd_rn(half_s[0], half_s[1]);
        packed[n] = 0xFFFFFFFFFFFFFFFFull;
        if (n == 0) *loss_slot = 0.0f;
    } else if (bx < 132) {                // ---- en role
        int k = (bx - 128) * 256 + t;
        const float* row = cb + (size_t)k * DDIM;
        float half_s[2];
        #pragma unroll
        for (int h = 0; h < 2; ++h) {
            const float* p = row + h * 128;
            float r[8];
            #pragma unroll
            for (int j = 0; j < 8; ++j) r[j] = __fmul_rn(p[j], p[j]);
            #pragma unroll
            for (int i = 8; i < 128; i += 8) {
                #pragma unroll
                for (int j = 0; j < 8; ++j)
                    r[j] = __fadd_rn(r[j], __fmul_rn(p[i + j], p[i + j]));
            }
            half_s[h] = __fadd_rn(
                __fadd_rn(__fadd_rn(r[0], r[1]), __fadd_rn(r[2], r[3])),
                __fadd_rn(__fadd_rn(r[4], r[5]), __fadd_rn(r[6], r[7])));
        }
        ws_f[WS_EN + k] = __fadd_rn(half_s[0], half_s[1]);
    } else {                              // ---- transpose role
        int bt = bx - 132;
        int k0 = (bt & 15) * 64;
        int d0 = (bt >> 4) * 64;
        float* et = ws_f + WS_ET;
        #pragma unroll
        for (int p = 0; p < 4; ++p) {
            int r  = p * 16 + (t >> 4);
            int c4 = (t & 15) * 4;
            float4 v = *reinterpret_cast<const float4*>(
                cb + (size_t)(k0 + r) * DDIM + d0 + c4);
            tile[r][c4] = v.x; tile[r][c4+1] = v.y;
            tile[r][c4+2] = v.z; tile[r][c4+3] = v.w;
        }
        __syncthreads();
        #pragma unroll
        for (int s = 0; s < 16; ++s) {
            int dd = s * 4 + (t >> 6);
            int kk = t & 63;
            et[(size_t)(d0 + dd) * KCODE + k0 + kk] = tile[kk][dd];
        }
    }
}

// ---------------------------------------------------------------------------
// K2: distance-GEMM + argmin, wave-uniform-A structure.
//   Block: 512 threads = 8 waves. Wave w owns positions n0+8w .. n0+8w+7
//   (WAVE-UNIFORM) and its 64 lanes x 8 codes cover 512 codes (kc half).
//   A (z values) -> uniform scalar loads (SMEM path via readfirstlane-forced
//   uniform address); B (codes) -> LDS with proven 9/8 skew (all-distinct
//   banks). DS pipe carries only B: 2 ds_read_b128 / wave / dk -> VALU-bound.
// Per-(n,k): sequential fmaf chain d=0..255 ascending, then
// fl(fl(zn+en)-fl(2*dot)) — BIT-IDENTICAL to the verified round-3/4 kernels.
// Cross-block merge: atomicMin on (f32bits(d)<<32)|k (d>0 -> monotone bits;
// ties -> smaller k == np.argmin first-index).
#define BM 64
#define BN 512
#define BK 16
#define BSKEW(k) ((k) + ((k) >> 3))   // max 511+63=574 -> row len 576

__launch_bounds__(512, 4)
__global__ void vq_argmin(const float* __restrict__ z,
                          const float* __restrict__ ws_f,
                          unsigned long long* __restrict__ packed) {
    __shared__ float Bs[BK][576];    // [dk][skewed code]

    const float* ET  = ws_f + WS_ET;
    const float* znW = ws_f + WS_ZN;
    const float* enW = ws_f + WS_EN;

    int t  = threadIdx.x;
    int l  = t & 63;                              // lane in wave
    int w_ = __builtin_amdgcn_readfirstlane(t >> 6);  // wave id, forced SGPR
    int bc = blockIdx.x & 1;                      // code-range half
    int bm = blockIdx.x >> 1;
    int kc = bc * BN;
    int n0 = bm * BM;
    int b  = n0 >> 10, hw0 = n0 & 1023;
    // wave-uniform A pointer: this wave's 8 positions, d-major
    const float* zw = z + (size_t)b * BSTRIDE + hw0 + 8 * w_;

    float acc[8][8];
    #pragma unroll
    for (int j = 0; j < 8; ++j)
        #pragma unroll
        for (int c = 0; c < 8; ++c) acc[j][c] = 0.0f;

    for (int d0 = 0; d0 < DDIM; d0 += BK) {
        __syncthreads();
        #pragma unroll
        for (int i = 0; i < 4; ++i) {   // stage B: 16 dk x 512 floats, skewed
            int q = t + i * 512;
            int dk = q >> 7, m = q & 127;         // codes 4m..4m+3
            float4 v = *reinterpret_cast<const float4*>(
                ET + (size_t)(d0 + dk) * KCODE + kc + 4 * m);
            int ph = BSKEW(4 * m);
            *reinterpret_cast<float4*>(&Bs[dk][ph]) = v;
        }
        __syncthreads();

        #pragma unroll
        for (int dh = 0; dh < BK; dh += 4) {
            // uniform A window: 4 dk x 8 positions (scalar loads)
            float4 a0[4], a1[4];
            #pragma unroll
            for (int dd = 0; dd < 4; ++dd) {
                const float* ap = zw + (size_t)(d0 + dh + dd) * HW;
                a0[dd] = *reinterpret_cast<const float4*>(ap);
                a1[dd] = *reinterpret_cast<const float4*>(ap + 4);
            }
            #pragma unroll
            for (int dd = 0; dd < 4; ++dd) {
                int dk = dh + dd;
                float4 b0 = *reinterpret_cast<const float4*>(&Bs[dk][9 * l]);
                float4 b1 = *reinterpret_cast<const float4*>(&Bs[dk][9 * l + 4]);
                float a[8]  = {a0[dd].x, a0[dd].y, a0[dd].z, a0[dd].w,
                               a1[dd].x, a1[dd].y, a1[dd].z, a1[dd].w};
                float bb[8] = {b0.x, b0.y, b0.z, b0.w, b1.x, b1.y, b1.z, b1.w};
                #pragma unroll
                for (int j = 0; j < 8; ++j)
                    #pragma unroll
                    for (int c = 0; c < 8; ++c)
                        acc[j][c] = fmaf(a[j], bb[c], acc[j][c]);
            }
        }
    }

    // epilogue: d = fl(fl(zn+en) - fl(2*dot)); strict < keeps first index.
    // lane l covers codes kc+8l .. kc+8l+7 (k ascending with lane, then c).
    float znr[8];
    #pragma unroll
    for (int j = 0; j < 8; ++j) znr[j] = znW[n0 + 8 * w_ + j];
    float4 e0 = *reinterpret_cast<const float4*>(enW + kc + 8 * l);
    float4 e1 = *reinterpret_cast<const float4*>(enW + kc + 8 * l + 4);
    float en8[8] = {e0.x, e0.y, e0.z, e0.w, e1.x, e1.y, e1.z, e1.w};

    float m1[8];
    int   i1[8];
    #pragma unroll
    for (int j = 0; j < 8; ++j) { m1[j] = 1e30f; i1[j] = 0; }
    #pragma unroll
    for (int c = 0; c < 8; ++c) {
        int k = kc + 8 * l + c;
        float ek = en8[c];
        #pragma unroll
        for (int j = 0; j < 8; ++j) {
            float t1 = __fadd_rn(znr[j], ek);
            float d  = __fsub_rn(t1, __fmul_rn(2.0f, acc[j][c]));
            if (d < m1[j]) { m1[j] = d; i1[j] = k; }
        }
    }

    // cross-lane argmin over all 64 lanes (smaller index wins ties)
    #pragma unroll
    for (int j = 0; j < 8; ++j) {
        float a1v = m1[j];
        int   ii  = i1[j];
        #pragma unroll
        for (int off = 1; off < 64; off <<= 1) {
            float o1 = __shfl_xor(a1v, off, 64);
            int   oi = __shfl_xor(ii, off, 64);
            if (o1 < a1v || (o1 == a1v && oi < ii)) { a1v = o1; ii = oi; }
        }
        if (l == 0) {
            unsigned long long key =
                ((unsigned long long)__float_as_uint(a1v) << 32) |
                (unsigned long long)(unsigned)ii;
            atomicMin(&packed[n0 + 8 * w_ + j], key);
        }
    }
}

// ---------------------------------------------------------------------------
// K3: final index extract + gather zq, transpose to (B,D,H,W), indices as
// float, loss = 2*mean((zq-zp)^2).
__global__ void vq_gather(const float* __restrict__ z,
                          const float* __restrict__ cb,
                          const unsigned long long* __restrict__ packed,
                          float* __restrict__ out,
                          float* __restrict__ loss) {
    int n = blockIdx.x * 256 + threadIdx.x;
    int b = n >> 10, hw = n & 1023;
    int k = (int)(unsigned)(packed[n] & 0xFFFFFFFFull);
    const float* e  = cb + (size_t)k * DDIM;
    const float* zp = z + (size_t)b * BSTRIDE + hw;
    float* op = out + (size_t)b * BSTRIDE + hw;
    float s = 0.0f;
    #pragma unroll 4
    for (int d4 = 0; d4 < DDIM / 4; ++d4) {
        float4 ev = *reinterpret_cast<const float4*>(e + 4 * d4);
        float evs[4] = {ev.x, ev.y, ev.z, ev.w};
        #pragma unroll
        for (int q = 0; q < 4; ++q) {
            int d = 4 * d4 + q;
            float zv = zp[(size_t)d * HW];
            op[(size_t)d * HW] = evs[q];
            float df = evs[q] - zv;
            s = fmaf(df, df, s);
        }
    }
    out[OUT0_SIZE + n] = (float)k;

    #pragma unroll
    for (int off = 32; off > 0; off >>= 1) s += __shfl_down(s, off);
    __shared__ float red[4];
    int lane = threadIdx.x & 63, w = threadIdx.x >> 6;
    if (lane == 0) red[w] = s;
    __syncthreads();
    if (threadIdx.x == 0) {
        float tot = (red[0] + red[1] + red[2] + red[3]) * (2.0f / 8388608.0f);
        atomicAdd(loss, tot);
    }
}

// ---------------------------------------------------------------------------
extern "C" void kernel_launch(void* const* d_in, const int* in_sizes, int n_in,
                              void* d_out, int out_size, void* d_ws, size_t ws_size,
                              hipStream_t stream) {
    const float* z  = (const float*)d_in[0];
    const float* cb = (const float*)d_in[1];
    float* out  = (float*)d_out;
    float* ws_f = (float*)d_ws;
    unsigned long long* packed =
        (unsigned long long*)(ws_f + WS_PACKED);
    float* loss = out + OUT0_SIZE + OUT1_SIZE;

    vq_prep<<<196, 256, 0, stream>>>(z, cb, ws_f, packed, loss);
    vq_argmin<<<(NPOS / BM) * (KCODE / BN), 512, 0, stream>>>(z, ws_f, packed);
    vq_gather<<<NPOS / 256, 256, 0, stream>>>(z, cb, packed, out, loss);
}

// Round 7
// 355.257 us; speedup vs baseline: 1.4439x; 1.0955x over previous
//
#include <hip/hip_runtime.h>

// Problem constants
#define NPOS 32768          // B*H*W = 32*32*32
#define DDIM 256
#define KCODE 1024
#define HW 1024             // H*W
#define BSTRIDE (256*1024)  // D*H*W per batch element
#define OUT0_SIZE 8388608   // B*D*H*W
#define OUT1_SIZE 32768

// ws layout (4-byte units):
//  [0 .. 262143]        ET    : transposed codebook [d][k]        (float)
//  [262144 .. 327679]   zn2   : per-position pairwise HALVES      (float, 2*32768)
//  [327680 .. 328703]   en    : ||e_k||^2 numpy-pairwise f32      (float, 1024)
//  [328704 .. 394239]   packed: (f32bits(d)<<32)|k per pos        (u64, 32768)
#define WS_ET     0
#define WS_ZN2    262144
#define WS_EN     327680
#define WS_PACKED 328704   // *4 bytes is 8-aligned

typedef float f32x8 __attribute__((ext_vector_type(8)));

// Force a wave-uniform pointer into SGPRs, then load through the constant
// address space -> s_load_dwordx8 (SMEM path, zero VGPR/DS/VMEM-lane cost).
__device__ __forceinline__ const float* uniform_ptr(const float* p) {
    unsigned long long u = (unsigned long long)(uintptr_t)p;
    unsigned lo = __builtin_amdgcn_readfirstlane((unsigned)u);
    unsigned hi = __builtin_amdgcn_readfirstlane((unsigned)(u >> 32));
    return (const float*)(((unsigned long long)hi << 32) | lo);
}

// ---------------------------------------------------------------------------
// K1: fused prep. grid 324 blocks x 256 threads:
//   [0,256)   : zn halves (numpy pairwise 128-blocks) + packed init (+loss 0)
//   [256,260) : en[k] numpy-pairwise
//   [260,324) : 64x64 LDS-tiled transpose cb -> ET
// numpy pairwise for n=256 = fl(half0+half1), each half = 8-accumulator
// unrolled 128-block. We compute the two halves in separate threads (bitwise
// identical chains) and merge with __fadd_rn in vq_argmin.
__global__ void vq_prep(const float* __restrict__ z,
                        const float* __restrict__ cb,
                        float* __restrict__ ws_f,
                        unsigned long long* __restrict__ packed,
                        float* __restrict__ loss_slot) {
    __shared__ float tile[64][65];
    int bx = blockIdx.x;
    int t  = threadIdx.x;

    if (bx < 256) {                       // ---- zn-half role
        int p = t >> 1, h = t & 1;
        int n = bx * 128 + p;
        int b = n >> 10, hw = n & 1023;
        const float* base = z + (size_t)b * BSTRIDE + hw + (size_t)(h * 128) * HW;
        float r[8];
        #pragma unroll
        for (int j = 0; j < 8; ++j) {
            float v = base[(size_t)j * HW];
            r[j] = __fmul_rn(v, v);
        }
        #pragma unroll
        for (int i = 8; i < 128; i += 8) {
            #pragma unroll
            for (int j = 0; j < 8; ++j) {
                float v = base[(size_t)(i + j) * HW];
                r[j] = __fadd_rn(r[j], __fmul_rn(v, v));
            }
        }
        float half_s = __fadd_rn(
            __fadd_rn(__fadd_rn(r[0], r[1]), __fadd_rn(r[2], r[3])),
            __fadd_rn(__fadd_rn(r[4], r[5]), __fadd_rn(r[6], r[7])));
        ws_f[WS_ZN2 + 2 * n + h] = half_s;
        if (h == 0) packed[n] = 0xFFFFFFFFFFFFFFFFull;
        if (bx == 0 && t == 0) *loss_slot = 0.0f;
    } else if (bx < 260) {                // ---- en role
        int k = (bx - 256) * 256 + t;
        const float* row = cb + (size_t)k * DDIM;
        float half_s[2];
        #pragma unroll
        for (int h = 0; h < 2; ++h) {
            const float* p2 = row + h * 128;
            float r[8];
            #pragma unroll
            for (int j = 0; j < 8; ++j) r[j] = __fmul_rn(p2[j], p2[j]);
            #pragma unroll
            for (int i = 8; i < 128; i += 8) {
                #pragma unroll
                for (int j = 0; j < 8; ++j)
                    r[j] = __fadd_rn(r[j], __fmul_rn(p2[i + j], p2[i + j]));
            }
            half_s[h] = __fadd_rn(
                __fadd_rn(__fadd_rn(r[0], r[1]), __fadd_rn(r[2], r[3])),
                __fadd_rn(__fadd_rn(r[4], r[5]), __fadd_rn(r[6], r[7])));
        }
        ws_f[WS_EN + k] = __fadd_rn(half_s[0], half_s[1]);
    } else {                              // ---- transpose role
        int bt = bx - 260;
        int k0 = (bt & 15) * 64;
        int d0 = (bt >> 4) * 64;
        float* et = ws_f + WS_ET;
        #pragma unroll
        for (int p = 0; p < 4; ++p) {
            int r  = p * 16 + (t >> 4);
            int c4 = (t & 15) * 4;
            float4 v = *reinterpret_cast<const float4*>(
                cb + (size_t)(k0 + r) * DDIM + d0 + c4);
            tile[r][c4] = v.x; tile[r][c4+1] = v.y;
            tile[r][c4+2] = v.z; tile[r][c4+3] = v.w;
        }
        __syncthreads();
        #pragma unroll
        for (int s = 0; s < 16; ++s) {
            int dd = s * 4 + (t >> 6);
            int kk = t & 63;
            et[(size_t)(d0 + dd) * KCODE + k0 + kk] = tile[kk][dd];
        }
    }
}

// ---------------------------------------------------------------------------
// K2: distance-GEMM + argmin. Block: 512 threads = 8 waves; wave w owns
// positions n0+8w..n0+8w+7 (wave-uniform) and 64 lanes x 8 codes = 512 codes.
// A: SMEM scalar loads (s_load_dwordx8 via AS(4)) -> SGPRs, feeds v_fma as
// the scalar operand. B: LDS, proven 9/8 skew (9 coprime 32, conflict-free).
// DS pipe carries only B: 2 ds_read_b128/wave/dk -> DS:VALU = 0.75, VALU-bound.
// Per-(n,k): sequential fmaf chain d=0..255 ascending, then
// fl(fl(zn+en)-fl(2*dot)) — BIT-IDENTICAL to verified rounds 3-6.
// zn reconstructed as __fadd_rn(half0,half1) == previous zn bitwise.
// Cross-block merge: atomicMin on (f32bits(d)<<32)|k.
#define BM 64
#define BN 512
#define BK 16
#define BSKEW(k) ((k) + ((k) >> 3))   // max 511+63=574 -> row len 576

__launch_bounds__(512, 4)
__global__ void vq_argmin(const float* __restrict__ z,
                          const float* __restrict__ ws_f,
                          unsigned long long* __restrict__ packed) {
    __shared__ float Bs[BK][576];    // [dk][skewed code]

    const float* ET  = ws_f + WS_ET;
    const float* zn2 = ws_f + WS_ZN2;
    const float* enW = ws_f + WS_EN;

    int t  = threadIdx.x;
    int l  = t & 63;                              // lane in wave
    int w_ = __builtin_amdgcn_readfirstlane(t >> 6);  // wave id (SGPR)
    int bc = blockIdx.x & 1;                      // code-range half
    int bm = blockIdx.x >> 1;
    int kc = bc * BN;
    int n0 = bm * BM;
    int b  = n0 >> 10, hw0 = n0 & 1023;
    // wave-uniform A base: this wave's 8 positions, d-major; 32B-aligned.
    const __attribute__((address_space(4))) f32x8* zc =
        (const __attribute__((address_space(4))) f32x8*)(uintptr_t)
            uniform_ptr(z + (size_t)b * BSTRIDE + hw0 + 8 * w_);

    float acc[8][8];
    #pragma unroll
    for (int j = 0; j < 8; ++j)
        #pragma unroll
        for (int c = 0; c < 8; ++c) acc[j][c] = 0.0f;

    for (int d0 = 0; d0 < DDIM; d0 += BK) {
        __syncthreads();
        #pragma unroll
        for (int i = 0; i < 4; ++i) {   // stage B: 16 dk x 512 floats, skewed
            int q = t + i * 512;
            int dk = q >> 7, m = q & 127;         // codes 4m..4m+3
            float4 v = *reinterpret_cast<const float4*>(
                ET + (size_t)(d0 + dk) * KCODE + kc + 4 * m);
            int ph = BSKEW(4 * m);
            *reinterpret_cast<float4*>(&Bs[dk][ph]) = v;
        }
        __syncthreads();

        #pragma unroll
        for (int dh = 0; dh < BK; dh += 4) {
            // A window: 4 dk x 8 positions, scalar loads (SGPRs)
            f32x8 aw[4];
            #pragma unroll
            for (int dd = 0; dd < 4; ++dd)
                aw[dd] = zc[(size_t)(d0 + dh + dd) * (HW / 8)];
            // B window: 4 dk x 8 codes (VGPRs)
            float4 b0[4], b1[4];
            #pragma unroll
            for (int dd = 0; dd < 4; ++dd) {
                b0[dd] = *reinterpret_cast<const float4*>(&Bs[dh + dd][9 * l]);
                b1[dd] = *reinterpret_cast<const float4*>(&Bs[dh + dd][9 * l + 4]);
            }
            #pragma unroll
            for (int dd = 0; dd < 4; ++dd) {
                float bb[8] = {b0[dd].x, b0[dd].y, b0[dd].z, b0[dd].w,
                               b1[dd].x, b1[dd].y, b1[dd].z, b1[dd].w};
                #pragma unroll
                for (int j = 0; j < 8; ++j) {
                    float aj = aw[dd][j];
                    #pragma unroll
                    for (int c = 0; c < 8; ++c)
                        acc[j][c] = fmaf(aj, bb[c], acc[j][c]);
                }
            }
        }
    }

    // epilogue: d = fl(fl(zn+en) - fl(2*dot)); strict < keeps first index.
    float znr[8];
    #pragma unroll
    for (int j = 0; j < 8; ++j) {
        int n = n0 + 8 * w_ + j;
        znr[j] = __fadd_rn(zn2[2 * n], zn2[2 * n + 1]);
    }
    float4 e0 = *reinterpret_cast<const float4*>(enW + kc + 8 * l);
    float4 e1 = *reinterpret_cast<const float4*>(enW + kc + 8 * l + 4);
    float en8[8] = {e0.x, e0.y, e0.z, e0.w, e1.x, e1.y, e1.z, e1.w};

    float m1[8];
    int   i1[8];
    #pragma unroll
    for (int j = 0; j < 8; ++j) { m1[j] = 1e30f; i1[j] = 0; }
    #pragma unroll
    for (int c = 0; c < 8; ++c) {
        int k = kc + 8 * l + c;
        float ek = en8[c];
        #pragma unroll
        for (int j = 0; j < 8; ++j) {
            float t1 = __fadd_rn(znr[j], ek);
            float d  = __fsub_rn(t1, __fmul_rn(2.0f, acc[j][c]));
            if (d < m1[j]) { m1[j] = d; i1[j] = k; }
        }
    }

    // cross-lane argmin over all 64 lanes (smaller index wins ties)
    #pragma unroll
    for (int j = 0; j < 8; ++j) {
        float a1v = m1[j];
        int   ii  = i1[j];
        #pragma unroll
        for (int off = 1; off < 64; off <<= 1) {
            float o1 = __shfl_xor(a1v, off, 64);
            int   oi = __shfl_xor(ii, off, 64);
            if (o1 < a1v || (o1 == a1v && oi < ii)) { a1v = o1; ii = oi; }
        }
        if (l == 0) {
            unsigned long long key =
                ((unsigned long long)__float_as_uint(a1v) << 32) |
                (unsigned long long)(unsigned)ii;
            atomicMin(&packed[n0 + 8 * w_ + j], key);
        }
    }
}

// ---------------------------------------------------------------------------
// K3: index extract + gather zq + transpose to (B,D,H,W) + loss.
// grid 512 blocks x 256 threads: block = 64 positions x 4 d-chunks of 64.
// Wave-uniform d-chunk, lane = position -> fully coalesced z/out traffic.
__global__ void vq_gather(const float* __restrict__ z,
                          const float* __restrict__ cb,
                          const unsigned long long* __restrict__ packed,
                          float* __restrict__ out,
                          float* __restrict__ loss) {
    int t  = threadIdx.x;
    int p  = t & 63, dc = t >> 6;
    int n  = blockIdx.x * 64 + p;
    int b  = n >> 10, hw = n & 1023;
    int k  = (int)(unsigned)(packed[n] & 0xFFFFFFFFull);
    size_t off = (size_t)b * BSTRIDE + hw + (size_t)(dc * 64) * HW;
    const float* e  = cb + (size_t)k * DDIM + dc * 64;
    const float* zp = z + off;
    float* op = out + off;
    float s = 0.0f;
    #pragma unroll 4
    for (int d4 = 0; d4 < 16; ++d4) {
        float4 ev = *reinterpret_cast<const float4*>(e + 4 * d4);
        float evs[4] = {ev.x, ev.y, ev.z, ev.w};
        #pragma unroll
        for (int q = 0; q < 4; ++q) {
            int d = 4 * d4 + q;
            float zv = zp[(size_t)d * HW];
            op[(size_t)d * HW] = evs[q];
            float df = evs[q] - zv;
            s = fmaf(df, df, s);
        }
    }
    if (dc == 0) out[OUT0_SIZE + n] = (float)k;

    #pragma unroll
    for (int o = 32; o > 0; o >>= 1) s += __shfl_down(s, o);
    __shared__ float red[4];
    int lane = t & 63, w = t >> 6;
    if (lane == 0) red[w] = s;
    __syncthreads();
    if (t == 0) {
        float tot = (red[0] + red[1] + red[2] + red[3]) * (2.0f / 8388608.0f);
        atomicAdd(loss, tot);
    }
}

// ---------------------------------------------------------------------------
extern "C" void kernel_launch(void* const* d_in, const int* in_sizes, int n_in,
                              void* d_out, int out_size, void* d_ws, size_t ws_size,
                              hipStream_t stream) {
    const float* z  = (const float*)d_in[0];
    const float* cb = (const float*)d_in[1];
    float* out  = (float*)d_out;
    float* ws_f = (float*)d_ws;
    unsigned long long* packed =
        (unsigned long long*)(ws_f + WS_PACKED);
    float* loss = out + OUT0_SIZE + OUT1_SIZE;

    vq_prep<<<324, 256, 0, stream>>>(z, cb, ws_f, packed, loss);
    vq_argmin<<<(NPOS / BM) * (KCODE / BN), 512, 0, stream>>>(z, ws_f, packed);
    vq_gather<<<NPOS / 64, 256, 0, stream>>>(z, cb, packed, out, loss);
}